// Round 1
// 636.814 us; speedup vs baseline: 1.0050x; 1.0050x over previous
//
#include <hip/hip_runtime.h>
#include <math.h>

// Problem constants (fixed by the reference)
#define B_ROWS 4096
#define C_COLS 32768
#define BLOCK  512
#define NWAVES (BLOCK / 64)            // 8 waves per block
#define NF4    (C_COLS / 4 / BLOCK)    // 16 float4 per thread (64 data VGPRs)

typedef float v4f __attribute__((ext_vector_type(4)));

static_assert(NF4 * BLOCK * 4 == C_COLS, "tiling must cover the row exactly");

__device__ __forceinline__ float wave_reduce_sum(float v) {
    #pragma unroll
    for (int off = 32; off > 0; off >>= 1)
        v += __shfl_down(v, off, 64);
    return v;
}

// Block-wide sum over NWAVES waves. `red` must have >= NWAVES floats.
// Two barriers; caller passes a distinct `red` per concurrent use.
__device__ __forceinline__ float block_reduce_sum(float v, float* red, int tid) {
    const int wid  = tid >> 6;
    const int lane = tid & 63;
    v = wave_reduce_sum(v);
    if (lane == 0) red[wid] = v;
    __syncthreads();
    if (wid == 0) {
        float s = (lane < NWAVES) ? red[lane] : 0.0f;
        #pragma unroll
        for (int off = NWAVES / 2; off > 0; off >>= 1)
            s += __shfl_down(s, off, 64);
        if (lane == 0) red[0] = s;
    }
    __syncthreads();
    return red[0];
}

// __launch_bounds__(512, 4): 4 waves/EU min -> 16 waves/CU = 2 blocks/CU,
// VGPR budget 512/4 = 128. Row data needs 64 VGPRs (16 x float4) + addr +
// reduce temps ~= 100 total -> no scratch spill (the old 1024x8 config
// capped VGPRs at 64 with 32 data regs live across two barriers -> spill).
__global__ __launch_bounds__(BLOCK, 4)
void focal_row_kernel(const float* __restrict__ inp,
                      const int*   __restrict__ tgt,
                      float*       __restrict__ row_loss) {
    constexpr float SCALE = 30.0f;
    constexpr float COSM  = 0.9553364891f;   // cos(0.3)
    constexpr float SINM  = 0.2955202067f;   // sin(0.3)

    const int row = blockIdx.x;
    const int tid = threadIdx.x;

    const v4f* __restrict__ rowp = (const v4f*)(inp + (size_t)row * C_COLS);

    __shared__ float red_a[NWAVES];
    __shared__ float red_b[NWAVES];

    // Thread 0 fetches the target element directly; stays in its registers.
    float xt = 0.0f;
    if (tid == 0) {
        const int ct = tgt[row];
        xt = inp[(size_t)row * C_COLS + ct];
    }

    // ---- Pass A: stream the row into registers (nontemporal: read-once),
    //      accumulate sum of squares with 4 independent chains ----
    v4f r[NF4];
    #pragma unroll
    for (int k = 0; k < NF4; ++k)
        r[k] = __builtin_nontemporal_load(rowp + (k * BLOCK + tid));

    float s0 = 0.0f, s1 = 0.0f, s2 = 0.0f, s3 = 0.0f;
    #pragma unroll
    for (int k = 0; k < NF4; ++k) {
        s0 = fmaf(r[k].x, r[k].x, s0);
        s1 = fmaf(r[k].y, r[k].y, s1);
        s2 = fmaf(r[k].z, r[k].z, s2);
        s3 = fmaf(r[k].w, r[k].w, s3);
    }
    const float sumsq = (s0 + s1) + (s2 + s3);

    const float total_sq = block_reduce_sum(sumsq, red_a, tid);
    const float norm = fmaxf(sqrtf(total_sq), 1e-12f);
    const float inv  = SCALE / norm;

    // ---- Pass B: sum of exp(scale * x / norm) from registers ----
    // |logit| <= 30 so fp32 exp is safe without max-subtraction.
    float e0 = 0.0f, e1 = 0.0f, e2 = 0.0f, e3 = 0.0f;
    #pragma unroll
    for (int k = 0; k < NF4; ++k) {
        e0 += __expf(r[k].x * inv);
        e1 += __expf(r[k].y * inv);
        e2 += __expf(r[k].z * inv);
        e3 += __expf(r[k].w * inv);
    }
    const float se = (e0 + e1) + (e2 + e3);
    const float sumexp_full = block_reduce_sum(se, red_b, tid);

    if (tid == 0) {
        const float c  = xt / norm;                         // cos(theta), unclipped
        const float cc = fminf(fmaxf(c, -1.0f + 1e-7f), 1.0f - 1e-7f);
        // cos(theta + m) = c*cos(m) - sqrt(1-c^2)*sin(m)
        const float sin_t = sqrtf(fmaxf(1.0f - cc * cc, 0.0f));
        const float cosm  = cc * COSM - sin_t * SINM;
        const float lt    = SCALE * cosm;                   // target logit

        // replace target term in the partition function
        const float Z  = sumexp_full - __expf(SCALE * c) + __expf(lt);
        const float ce = logf(Z) - lt;                      // -log_softmax[target]
        const float pt = __expf(-ce);
        const float om = 1.0f - pt;
        row_loss[row] = om * om * ce;                       // gamma = 2.0
    }
}

// Single block: mean of 4096 per-row losses -> out[0]. Plain store (no
// memset / atomic needed; d_ws is fully written by the row kernel first).
__global__ __launch_bounds__(1024)
void finalize_kernel(const float* __restrict__ row_loss,
                     float*       __restrict__ out) {
    const int tid = threadIdx.x;
    __shared__ float red[16];
    const int wid  = tid >> 6;
    const int lane = tid & 63;
    float s = 0.0f;
    #pragma unroll
    for (int k = 0; k < B_ROWS / 1024; ++k)
        s += row_loss[k * 1024 + tid];
    s = wave_reduce_sum(s);
    if (lane == 0) red[wid] = s;
    __syncthreads();
    if (wid == 0) {
        float t = (lane < 16) ? red[lane] : 0.0f;
        #pragma unroll
        for (int off = 8; off > 0; off >>= 1)
            t += __shfl_down(t, off, 64);
        if (lane == 0) out[0] = t * (1.0f / (float)B_ROWS);
    }
}

extern "C" void kernel_launch(void* const* d_in, const int* in_sizes, int n_in,
                              void* d_out, int out_size, void* d_ws, size_t ws_size,
                              hipStream_t stream) {
    const float* inp = (const float*)d_in[0];
    const int*   tgt = (const int*)d_in[1];
    float*       out = (float*)d_out;
    float*       row_loss = (float*)d_ws;   // 4096 floats = 16 KB of scratch

    focal_row_kernel<<<B_ROWS, BLOCK, 0, stream>>>(inp, tgt, row_loss);
    finalize_kernel<<<1, 1024, 0, stream>>>(row_loss, out);
}